// Round 1
// baseline (5295.641 us; speedup 1.0000x reference)
//
#include <hip/hip_runtime.h>
#include <math.h>

#define N_NODES 30000
#define N_EDGES 480000
#define N_GRAPHS 16
#define HID 128
#define HEADS 8
#define HEAD_DIM 16
#define NODE_IN 64
#define EDGE_IN 32
#define COND 8
#define NODE_OUT 64
#define NLAYERS 4
#define EF (N_EDGES + N_NODES) /* 510000 */
#define LN_EPS 1e-5f

#define ATILE 64        /* edges per att block */
#define EA_STRIDE 132   /* sh_ea row stride in floats: 4-float aligned, rows rg+8i conflict-free */

__device__ __forceinline__ float gelu_f(float x) {
    return 0.5f * x * (1.0f + erff(x * 0.70710678118654752440f));
}

__device__ __forceinline__ void atomicMaxF(float* addr, float val) {
    if (val >= 0.0f) {
        atomicMax((int*)addr, __float_as_int(val));
    } else {
        atomicMin((unsigned int*)addr, __float_as_uint(val));
    }
}

// ---------- generic zero ----------
__global__ void zero_kernel(float* __restrict__ p, long n) {
    long i = (long)blockIdx.x * blockDim.x + threadIdx.x;
    long stride = (long)gridDim.x * blockDim.x;
    for (; i < n; i += stride) p[i] = 0.0f;
}

// ---------- time MLP: t[16] -> t_emb[16,128] ----------
__global__ void time_mlp_kernel(const float* __restrict__ t,
                                const float* __restrict__ tW1, const float* __restrict__ tb1,
                                const float* __restrict__ tW2, const float* __restrict__ tb2,
                                float* __restrict__ t_emb) {
    __shared__ float hsh[HID];
    int b = blockIdx.x, j = threadIdx.x;
    float tv = t[b];
    hsh[j] = gelu_f(tv * tW1[j] + tb1[j]);
    __syncthreads();
    float acc = tb2[j];
    for (int k = 0; k < HID; ++k) acc += hsh[k] * tW2[k * HID + j];
    t_emb[b * HID + j] = acc;
}

// ---------- concat x(64) + conditions[batch](8) -> xc[N,72] ----------
__global__ void concat_kernel(const float* __restrict__ x, const float* __restrict__ cond,
                              const int* __restrict__ batch, float* __restrict__ xc) {
    int idx = blockIdx.x * blockDim.x + threadIdx.x;
    if (idx >= N_NODES * 72) return;
    int n = idx / 72, c = idx % 72;
    xc[idx] = (c < NODE_IN) ? x[n * NODE_IN + c] : cond[batch[n] * COND + (c - NODE_IN)];
}

// ---------- generic GEMM: C[M,NCOL] = A[M,K] @ B[K,NCOL] + bias ----------
template <int NCOL, int R>
__global__ void gemm_kernel(const float* __restrict__ A, const float* __restrict__ B,
                            const float* __restrict__ bias, float* __restrict__ C,
                            int M, int K) {
    __shared__ float sh[R * HID];
    int j = threadIdx.x;
    int row0 = blockIdx.x * R;
    int total = R * K;
    for (int i = j; i < total; i += NCOL) {
        int r = i / K, k = i - r * K;
        int row = row0 + r;
        sh[r * K + k] = (row < M) ? A[(long)row * K + k] : 0.0f;
    }
    __syncthreads();
    float acc[R];
    float bv = bias ? bias[j] : 0.0f;
#pragma unroll
    for (int r = 0; r < R; ++r) acc[r] = bv;
    for (int k = 0; k < K; ++k) {
        float w = B[k * NCOL + j];
#pragma unroll
        for (int r = 0; r < R; ++r) acc[r] += sh[r * K + k] * w;
    }
#pragma unroll
    for (int r = 0; r < R; ++r) {
        int row = row0 + r;
        if (row < M) C[(long)row * NCOL + j] = acc[r];
    }
}

// ---------- in-place LayerNorm + GELU (+ optional t_emb[batch[row]]) ----------
__global__ void ln_gelu_kernel(float* __restrict__ X, const float* __restrict__ g,
                               const float* __restrict__ bta,
                               const float* __restrict__ t_emb, const int* __restrict__ batch) {
    int row = blockIdx.x, j = threadIdx.x;
    __shared__ float red[HID];
    float v = X[(long)row * HID + j];
    red[j] = v;
    __syncthreads();
    for (int s = 64; s > 0; s >>= 1) { if (j < s) red[j] += red[j + s]; __syncthreads(); }
    float mean = red[0] * (1.0f / HID);
    __syncthreads();
    float d = v - mean;
    red[j] = d * d;
    __syncthreads();
    for (int s = 64; s > 0; s >>= 1) { if (j < s) red[j] += red[j + s]; __syncthreads(); }
    float var = red[0] * (1.0f / HID);
    float y = gelu_f(d * rsqrtf(var + LN_EPS) * g[j] + bta[j]);
    if (t_emb) y += t_emb[batch[row] * HID + j];
    X[(long)row * HID + j] = y;
}

// ---------- fused: edge-encode + segment-sum into loop_sum/cnt ----------
template <int R>
__global__ void edge_enc_loop_kernel(const float* __restrict__ edge_attr,
                                     const float* __restrict__ eW, const float* __restrict__ eb,
                                     const float* __restrict__ eg, const float* __restrict__ ebe,
                                     const int* __restrict__ ei_dst,
                                     float* __restrict__ loop_sum, float* __restrict__ cnt) {
    __shared__ float red[R * HID];
    __shared__ float sattr[R * EDGE_IN];
    __shared__ int sdst[R];
    int j = threadIdx.x;
    long e0 = (long)blockIdx.x * R;
    for (int i = j; i < R * EDGE_IN; i += HID) {
        int r = i >> 5, k = i & 31;
        long e = e0 + r;
        if (e < N_EDGES) sattr[i] = edge_attr[e * EDGE_IN + k];
    }
    if (j < R) {
        long e = e0 + j;
        if (e < N_EDGES) sdst[j] = ei_dst[e];
    }
    __syncthreads();
    float val[R];
#pragma unroll
    for (int r = 0; r < R; ++r) {
        float v = eb[j];
        for (int k = 0; k < EDGE_IN; ++k) v += sattr[r * EDGE_IN + k] * eW[k * HID + j];
        val[r] = v;
        red[r * HID + j] = v;
    }
    __syncthreads();
    for (int s = 64; s > 0; s >>= 1) {
        if (j < s) {
#pragma unroll
            for (int r = 0; r < R; ++r) red[r * HID + j] += red[r * HID + j + s];
        }
        __syncthreads();
    }
    float mean[R];
#pragma unroll
    for (int r = 0; r < R; ++r) mean[r] = red[r * HID] * (1.0f / HID);
    __syncthreads();
#pragma unroll
    for (int r = 0; r < R; ++r) { float d = val[r] - mean[r]; red[r * HID + j] = d * d; }
    __syncthreads();
    for (int s = 64; s > 0; s >>= 1) {
        if (j < s) {
#pragma unroll
            for (int r = 0; r < R; ++r) red[r * HID + j] += red[r * HID + j + s];
        }
        __syncthreads();
    }
#pragma unroll
    for (int r = 0; r < R; ++r) {
        long e = e0 + r;
        if (e >= N_EDGES) break;
        float var = red[r * HID] * (1.0f / HID);
        float y = gelu_f((val[r] - mean[r]) * rsqrtf(var + LN_EPS) * eg[j] + ebe[j]);
        int d = sdst[r];
        atomicAdd(&loop_sum[(long)d * HID + j], y);
        if (j == 0) atomicAdd(&cnt[d], 1.0f);
    }
}

__global__ void loop_div_kernel(float* __restrict__ loop_attr, const float* __restrict__ cnt) {
    int idx = blockIdx.x * blockDim.x + threadIdx.x;
    if (idx >= N_NODES * HID) return;
    int n = idx >> 7;
    loop_attr[idx] = loop_attr[idx] / fmaxf(cnt[n], 1.0f);
}

// ---------- init mx=-inf, den=0 ----------
__global__ void init_mx_den_kernel(float* __restrict__ mx, float* __restrict__ den) {
    int idx = blockIdx.x * blockDim.x + threadIdx.x;
    if (idx >= N_NODES * HEADS) return;
    mx[idx] = -INFINITY;
    den[idx] = 0.0f;
}

// ---------- weight prep: k-tiled transposes ----------
// eWT4[kb][j][kk] = eW[kb*4+kk][j]   (8*128*4 floats)
// BT4 [l][kb][c][kk] = cWe[l][kb*4+kk][c]  (4*32*128*4 floats)
__global__ void prep_weights_kernel(const float* __restrict__ eW, const float* __restrict__ cWe,
                                    float* __restrict__ eWT4, float* __restrict__ BT4) {
    int idx = blockIdx.x * blockDim.x + threadIdx.x;
    if (idx < 8 * HID * 4) {
        int kb = idx >> 9, rem = idx & 511, j = rem >> 2, kk = rem & 3;
        eWT4[idx] = eW[(kb * 4 + kk) * HID + j];
    }
    if (idx < NLAYERS * 32 * HID * 4) {
        int l = idx >> 14, rem = idx & 16383;
        int kb = rem >> 9, r2 = rem & 511, c = r2 >> 2, kk = r2 & 3;
        BT4[idx] = cWe[l * HID * HID + (kb * 4 + kk) * HID + c];
    }
}

// ---------- tiled fused: edge-encode + em GEMM + leakyrelu + logit + atomicMax ----------
// Block: 256 threads, 64 edges.
// Encode phase: wave w owns rows w*16..w*16+15; lane holds cols (lane, lane+64);
//               LN via one-pass sum/sumsq shfl_xor reduce (no barriers).
// GEMM phase:  rg = t&7, cg = t>>3; rows rg+8i (i<8), cols cg*4..cg*4+3.
//              sh_ea stride 132 -> 8 concurrent b128 row-reads land on disjoint bank quads.
template <bool SELFLOOP>
__global__ __launch_bounds__(256) void att_logit2_kernel(
        const float* __restrict__ edge_attr,
        const float* __restrict__ eWT4,
        const float* __restrict__ eb, const float* __restrict__ eg, const float* __restrict__ ebe,
        const float* __restrict__ loop_attr,
        const float* __restrict__ BT4_l,   /* [32][128][4] this layer */
        const float* __restrict__ catt_l,  /* [128] */
        const float* __restrict__ xl, const float* __restrict__ xr,
        const int* __restrict__ ei_src, const int* __restrict__ ei_dst,
        float* __restrict__ logit, float* __restrict__ mx) {
    __shared__ float sh_ea[ATILE * EA_STRIDE];
    __shared__ float sattr[ATILE * EDGE_IN];
    __shared__ int ssrc[ATILE], sdst[ATILE];
    int t = threadIdx.x;
    long e0 = (long)blockIdx.x * ATILE + (SELFLOOP ? N_EDGES : 0);

    // ---- phase 0: stage inputs ----
    if (!SELFLOOP) {
        const float4* ea4 = (const float4*)(edge_attr + e0 * EDGE_IN);
        float4* sa4 = (float4*)sattr;
#pragma unroll
        for (int i = 0; i < 2; ++i) sa4[t + i * 256] = ea4[t + i * 256];
        if (t < ATILE) ssrc[t] = ei_src[e0 + t];
        else if (t < 2 * ATILE) sdst[t - ATILE] = ei_dst[e0 + (t - ATILE)];
    } else {
        int n0 = (int)(e0 - N_EDGES);
        for (int i = t; i < ATILE * HID; i += 256) {
            int r = i >> 7, j = i & 127;
            int n = n0 + r;
            sh_ea[r * EA_STRIDE + j] = (n < N_NODES) ? loop_attr[(long)n * HID + j] : 0.0f;
        }
        if (t < ATILE) { int n = n0 + t; ssrc[t] = sdst[t] = (n < N_NODES) ? n : 0; }
    }
    __syncthreads();

    // ---- phase 1: encode (real edges only) ----
    if (!SELFLOOP) {
        int lane = t & 63, w = t >> 6;
        int j1 = lane, j2 = lane + 64;
        float ebv0 = eb[j1], ebv1 = eb[j2];
        float egv0 = eg[j1], egv1 = eg[j2];
        float bev0 = ebe[j1], bev1 = ebe[j2];
        const float4* EW4 = (const float4*)eWT4;
#pragma unroll
        for (int p = 0; p < 2; ++p) {
            int r0 = w * 16 + p * 8;
            float v0[8], v1[8];
#pragma unroll
            for (int q = 0; q < 8; ++q) { v0[q] = ebv0; v1[q] = ebv1; }
#pragma unroll
            for (int kb = 0; kb < 8; ++kb) {
                float4 w0 = EW4[kb * HID + j1];
                float4 w1 = EW4[kb * HID + j2];
#pragma unroll
                for (int q = 0; q < 8; ++q) {
                    float4 av = *(const float4*)&sattr[(r0 + q) * EDGE_IN + kb * 4];
                    v0[q] += av.x * w0.x + av.y * w0.y + av.z * w0.z + av.w * w0.w;
                    v1[q] += av.x * w1.x + av.y * w1.y + av.z * w1.z + av.w * w1.w;
                }
            }
#pragma unroll
            for (int q = 0; q < 8; ++q) {
                float s1 = v0[q] + v1[q];
                float s2 = v0[q] * v0[q] + v1[q] * v1[q];
#pragma unroll
                for (int m = 1; m < 64; m <<= 1) {
                    s1 += __shfl_xor(s1, m);
                    s2 += __shfl_xor(s2, m);
                }
                float mean = s1 * (1.0f / 128.0f);
                float var = s2 * (1.0f / 128.0f) - mean * mean;
                float rs = rsqrtf(var + LN_EPS);
                sh_ea[(r0 + q) * EA_STRIDE + j1] = gelu_f((v0[q] - mean) * rs * egv0 + bev0);
                sh_ea[(r0 + q) * EA_STRIDE + j2] = gelu_f((v1[q] - mean) * rs * egv1 + bev1);
            }
        }
    }
    __syncthreads();

    // ---- phase 2: em GEMM, register-tiled 8x4 ----
    int rg = t & 7, cg = t >> 3;
    int c0 = cg * 4;
    float acc[8][4];
#pragma unroll
    for (int i = 0; i < 8; ++i)
#pragma unroll
        for (int c = 0; c < 4; ++c) acc[i][c] = 0.0f;
    const float4* B4 = (const float4*)BT4_l;
#pragma unroll 2
    for (int kb = 0; kb < 32; ++kb) {
        float4 b0 = B4[kb * HID + c0 + 0];
        float4 b1 = B4[kb * HID + c0 + 1];
        float4 b2 = B4[kb * HID + c0 + 2];
        float4 b3 = B4[kb * HID + c0 + 3];
#pragma unroll
        for (int i = 0; i < 8; ++i) {
            float4 a = *(const float4*)&sh_ea[(rg + 8 * i) * EA_STRIDE + kb * 4];
            acc[i][0] += a.x * b0.x + a.y * b0.y + a.z * b0.z + a.w * b0.w;
            acc[i][1] += a.x * b1.x + a.y * b1.y + a.z * b1.z + a.w * b1.w;
            acc[i][2] += a.x * b2.x + a.y * b2.y + a.z * b2.z + a.w * b2.w;
            acc[i][3] += a.x * b3.x + a.y * b3.y + a.z * b3.z + a.w * b3.w;
        }
    }

    // ---- phase 3: logit + atomic max ----
    float4 cattv = *(const float4*)&catt_l[c0];
    int head = cg >> 2;
#pragma unroll
    for (int i = 0; i < 8; ++i) {
        int r = rg + 8 * i;
        long e = e0 + r;
        int s = ssrc[r], d = sdst[r];
        float4 xlv = *(const float4*)&xl[(long)s * HID + c0];
        float4 xrv = *(const float4*)&xr[(long)d * HID + c0];
        float m0 = xlv.x + xrv.x + acc[i][0]; m0 = (m0 > 0.0f) ? m0 : 0.2f * m0;
        float m1 = xlv.y + xrv.y + acc[i][1]; m1 = (m1 > 0.0f) ? m1 : 0.2f * m1;
        float m2 = xlv.z + xrv.z + acc[i][2]; m2 = (m2 > 0.0f) ? m2 : 0.2f * m2;
        float m3 = xlv.w + xrv.w + acc[i][3]; m3 = (m3 > 0.0f) ? m3 : 0.2f * m3;
        float p = m0 * cattv.x + m1 * cattv.y + m2 * cattv.z + m3 * cattv.w;
        p += __shfl_xor(p, 8);
        p += __shfl_xor(p, 16);
        if ((cg & 3) == 0) {
            if (!SELFLOOP || e < (long)EF) {
                logit[e * HEADS + head] = p;
                atomicMaxF(&mx[(long)d * HEADS + head], p);
            }
        }
    }
}

// ---------- exp(logit-mx), accumulate denominator ----------
__global__ void softmax_norm_kernel(const int* __restrict__ ei_dst, const float* __restrict__ mx,
                                    float* __restrict__ logit, float* __restrict__ den) {
    long idx = (long)blockIdx.x * blockDim.x + threadIdx.x;
    if (idx >= (long)EF * HEADS) return;
    long e = idx >> 3;
    int hh = (int)(idx & 7);
    int d = (e < N_EDGES) ? ei_dst[e] : (int)(e - N_EDGES);
    float ex = expf(logit[idx] - mx[(long)d * HEADS + hh]);
    logit[idx] = ex;
    atomicAdd(&den[(long)d * HEADS + hh], ex);
}

// ---------- alpha-weighted aggregation ----------
__global__ void aggregate_kernel(const float* __restrict__ logit, const float* __restrict__ den,
                                 const float* __restrict__ xl,
                                 const int* __restrict__ ei_src, const int* __restrict__ ei_dst,
                                 float* __restrict__ aggout) {
    long idx = (long)blockIdx.x * blockDim.x + threadIdx.x;
    if (idx >= (long)EF * HID) return;
    long e = idx >> 7;
    int j = (int)(idx & 127);
    int s, d;
    if (e < N_EDGES) { s = ei_src[e]; d = ei_dst[e]; }
    else             { s = d = (int)(e - N_EDGES); }
    int head = j >> 4;
    float alpha = logit[e * HEADS + head] / (den[(long)d * HEADS + head] + 1e-16f);
    atomicAdd(&aggout[(long)d * HID + j], alpha * xl[(long)s * HID + j]);
}

// ---------- h = gelu(aggout + cbias) + h ----------
__global__ void residual_kernel(const float* __restrict__ aggout, const float* __restrict__ cbias_l,
                                float* __restrict__ h) {
    int idx = blockIdx.x * blockDim.x + threadIdx.x;
    if (idx >= N_NODES * HID) return;
    int j = idx & 127;
    h[idx] = gelu_f(aggout[idx] + cbias_l[j]) + h[idx];
}

// ---------- pooling ----------
#define POOL_NODES 64
__global__ void pool_kernel(const float* __restrict__ h, const int* __restrict__ batch,
                            float* __restrict__ gsum, float* __restrict__ gcnt) {
    __shared__ float acc[N_GRAPHS][HID];
    __shared__ float cnt_sh[N_GRAPHS];
    int j = threadIdx.x;
    for (int g = 0; g < N_GRAPHS; ++g) acc[g][j] = 0.0f;
    if (j < N_GRAPHS) cnt_sh[j] = 0.0f;
    __syncthreads();
    int n0 = blockIdx.x * POOL_NODES;
    for (int i = 0; i < POOL_NODES; ++i) {
        int n = n0 + i;
        if (n >= N_NODES) break;
        int g = batch[n];
        acc[g][j] += h[(long)n * HID + j];
        if (j == 0) cnt_sh[g] += 1.0f;
    }
    __syncthreads();
    for (int g = 0; g < N_GRAPHS; ++g) atomicAdd(&gsum[g * HID + j], acc[g][j]);
    if (j < N_GRAPHS) atomicAdd(&gcnt[j], cnt_sh[j]);
}

// ---------- props head ----------
__global__ void props_kernel(const float* __restrict__ gsum, const float* __restrict__ gcnt,
                             const float* __restrict__ pW1, const float* __restrict__ pb1,
                             const float* __restrict__ pg, const float* __restrict__ pbe,
                             const float* __restrict__ pW2, const float* __restrict__ pb2,
                             float* __restrict__ out_props) {
    int g = blockIdx.x, j = threadIdx.x;
    __shared__ float feat[HID], red[HID], t2[HID];
    float c = fmaxf(gcnt[g], 1.0f);
    feat[j] = gsum[g * HID + j] / c;
    __syncthreads();
    float acc = pb1[j];
    for (int k = 0; k < HID; ++k) acc += feat[k] * pW1[k * HID + j];
    red[j] = acc;
    __syncthreads();
    for (int s = 64; s > 0; s >>= 1) { if (j < s) red[j] += red[j + s]; __syncthreads(); }
    float mean = red[0] * (1.0f / HID);
    __syncthreads();
    float dd = acc - mean;
    red[j] = dd * dd;
    __syncthreads();
    for (int s = 64; s > 0; s >>= 1) { if (j < s) red[j] += red[j + s]; __syncthreads(); }
    float var = red[0] * (1.0f / HID);
    t2[j] = gelu_f(dd * rsqrtf(var + LN_EPS) * pg[j] + pbe[j]);
    __syncthreads();
    if (j < COND) {
        float a = pb2[j];
        for (int k = 0; k < HID; ++k) a += t2[k] * pW2[k * COND + j];
        out_props[g * COND + j] = a;
    }
}

extern "C" void kernel_launch(void* const* d_in, const int* in_sizes, int n_in,
                              void* d_out, int out_size, void* d_ws, size_t ws_size,
                              hipStream_t stream) {
    const float* x        = (const float*)d_in[0];
    const float* edge_attr= (const float*)d_in[1];
    const float* t        = (const float*)d_in[2];
    const float* conds    = (const float*)d_in[3];
    const float* tW1      = (const float*)d_in[4];
    const float* tb1      = (const float*)d_in[5];
    const float* tW2      = (const float*)d_in[6];
    const float* tb2      = (const float*)d_in[7];
    const float* encW     = (const float*)d_in[8];
    const float* encb     = (const float*)d_in[9];
    const float* encg     = (const float*)d_in[10];
    const float* encbe    = (const float*)d_in[11];
    const float* eW       = (const float*)d_in[12];
    const float* eb       = (const float*)d_in[13];
    const float* eg       = (const float*)d_in[14];
    const float* ebe      = (const float*)d_in[15];
    const float* cWl      = (const float*)d_in[16];
    const float* cbl      = (const float*)d_in[17];
    const float* cWr      = (const float*)d_in[18];
    const float* cbr      = (const float*)d_in[19];
    const float* cWe      = (const float*)d_in[20];
    const float* catt     = (const float*)d_in[21];
    const float* cbias    = (const float*)d_in[22];
    const float* nW1      = (const float*)d_in[23];
    const float* nb1      = (const float*)d_in[24];
    const float* ng       = (const float*)d_in[25];
    const float* nbe      = (const float*)d_in[26];
    const float* nW2      = (const float*)d_in[27];
    const float* nb2      = (const float*)d_in[28];
    const float* pW1      = (const float*)d_in[29];
    const float* pb1      = (const float*)d_in[30];
    const float* pg       = (const float*)d_in[31];
    const float* pbe      = (const float*)d_in[32];
    const float* pW2      = (const float*)d_in[33];
    const float* pb2      = (const float*)d_in[34];
    const int* edge_index = (const int*)d_in[35];
    const int* batch      = (const int*)d_in[36];
    const int* ei_src = edge_index;
    const int* ei_dst = edge_index + N_EDGES;

    // workspace layout (~95 MB of f32)
    float* ws = (float*)d_ws;
    size_t off = 0;
    auto alloc = [&](size_t n) { float* p = ws + off; off += n; return p; };
    float* t_emb     = alloc((size_t)N_GRAPHS * HID);
    float* h         = alloc((size_t)N_NODES * HID);
    float* loop_attr = alloc((size_t)N_NODES * HID);
    float* cnt       = alloc((size_t)N_NODES);
    float* xl        = alloc((size_t)N_NODES * HID);
    float* xr        = alloc((size_t)N_NODES * HID);
    float* logit     = alloc((size_t)EF * HEADS);      // 4.08M floats
    float* mx        = alloc((size_t)N_NODES * HEADS);
    float* den       = alloc((size_t)N_NODES * HEADS);
    float* aggout    = alloc((size_t)N_NODES * HID);
    float* gsum      = alloc((size_t)N_GRAPHS * HID);
    float* gcnt      = alloc((size_t)N_GRAPHS);
    float* eWT4      = alloc((size_t)8 * HID * 4);          // k-tiled eW^T
    float* BT4       = alloc((size_t)NLAYERS * 32 * HID * 4); // k-tiled cWe^T per layer
    // aliases (disjoint lifetimes):
    float* xc   = logit;  // [N,72] = 2.16M floats, used only pre-layers; logit is 4.08M
    float* tmp1 = xl;     // used only post-layers
    (void)ws_size; (void)in_sizes; (void)n_in; (void)out_size;

    float* pred_noise = (float*)d_out;                              // [N,64]
    float* pred_props = (float*)d_out + (size_t)N_NODES * NODE_OUT; // [16,8]

    // 0. weight prep (k-tiled transposes for the att kernels)
    hipLaunchKernelGGL(prep_weights_kernel, dim3((NLAYERS * 32 * HID * 4 + 255) / 256), dim3(256),
                       0, stream, eW, cWe, eWT4, BT4);
    // 1. time MLP
    hipLaunchKernelGGL(time_mlp_kernel, dim3(N_GRAPHS), dim3(HID), 0, stream,
                       t, tW1, tb1, tW2, tb2, t_emb);
    // 2. concat
    hipLaunchKernelGGL(concat_kernel, dim3((N_NODES * 72 + 255) / 256), dim3(256), 0, stream,
                       x, conds, batch, xc);
    // 3. node encoder gemm + LN/GELU (+t_emb[batch])
    hipLaunchKernelGGL((gemm_kernel<HID, 8>), dim3(N_NODES / 8), dim3(HID), 0, stream,
                       xc, encW, encb, h, N_NODES, 72);
    hipLaunchKernelGGL(ln_gelu_kernel, dim3(N_NODES), dim3(HID), 0, stream,
                       h, encg, encbe, t_emb, batch);
    // 4. self-loop attr = segment-mean of encoded edge_attr over dst (encode fused)
    hipLaunchKernelGGL(zero_kernel, dim3(1024), dim3(256), 0, stream,
                       loop_attr, (long)N_NODES * HID);
    hipLaunchKernelGGL(zero_kernel, dim3(64), dim3(256), 0, stream, cnt, (long)N_NODES);
    hipLaunchKernelGGL((edge_enc_loop_kernel<8>), dim3(N_EDGES / 8), dim3(HID), 0, stream,
                       edge_attr, eW, eb, eg, ebe, ei_dst, loop_attr, cnt);
    hipLaunchKernelGGL(loop_div_kernel, dim3((N_NODES * HID + 255) / 256), dim3(256), 0, stream,
                       loop_attr, cnt);

    // 5. layers
    for (int l = 0; l < NLAYERS; ++l) {
        const float* cWl_l = cWl + (size_t)l * HID * HID;
        const float* cWr_l = cWr + (size_t)l * HID * HID;
        const float* BT4_l = BT4 + (size_t)l * 32 * HID * 4;
        const float* cbl_l = cbl + (size_t)l * HID;
        const float* cbr_l = cbr + (size_t)l * HID;
        const float* catt_l = catt + (size_t)l * HID;
        const float* cbias_l = cbias + (size_t)l * HID;

        hipLaunchKernelGGL((gemm_kernel<HID, 8>), dim3(N_NODES / 8), dim3(HID), 0, stream,
                           h, cWl_l, cbl_l, xl, N_NODES, HID);
        hipLaunchKernelGGL((gemm_kernel<HID, 8>), dim3(N_NODES / 8), dim3(HID), 0, stream,
                           h, cWr_l, cbr_l, xr, N_NODES, HID);
        hipLaunchKernelGGL(init_mx_den_kernel, dim3((N_NODES * HEADS + 255) / 256), dim3(256), 0,
                           stream, mx, den);
        hipLaunchKernelGGL((att_logit2_kernel<false>), dim3(N_EDGES / ATILE), dim3(256), 0, stream,
                           edge_attr, eWT4, eb, eg, ebe, loop_attr,
                           BT4_l, catt_l, xl, xr, ei_src, ei_dst, logit, mx);
        hipLaunchKernelGGL((att_logit2_kernel<true>), dim3((N_NODES + ATILE - 1) / ATILE), dim3(256),
                           0, stream,
                           edge_attr, eWT4, eb, eg, ebe, loop_attr,
                           BT4_l, catt_l, xl, xr, ei_src, ei_dst, logit, mx);
        hipLaunchKernelGGL(softmax_norm_kernel,
                           dim3((int)(((long)EF * HEADS + 255) / 256)), dim3(256), 0, stream,
                           ei_dst, mx, logit, den);
        hipLaunchKernelGGL(zero_kernel, dim3(1024), dim3(256), 0, stream,
                           aggout, (long)N_NODES * HID);
        hipLaunchKernelGGL(aggregate_kernel,
                           dim3((int)(((long)EF * HID + 255) / 256)), dim3(256), 0, stream,
                           logit, den, xl, ei_src, ei_dst, aggout);
        hipLaunchKernelGGL(residual_kernel, dim3((N_NODES * HID + 255) / 256), dim3(256), 0, stream,
                           aggout, cbias_l, h);
    }

    // 6. noise head
    hipLaunchKernelGGL((gemm_kernel<HID, 8>), dim3(N_NODES / 8), dim3(HID), 0, stream,
                       h, nW1, nb1, tmp1, N_NODES, HID);
    hipLaunchKernelGGL(ln_gelu_kernel, dim3(N_NODES), dim3(HID), 0, stream,
                       tmp1, ng, nbe, (const float*)nullptr, (const int*)nullptr);
    hipLaunchKernelGGL((gemm_kernel<NODE_OUT, 8>), dim3(N_NODES / 8), dim3(NODE_OUT), 0, stream,
                       tmp1, nW2, nb2, pred_noise, N_NODES, HID);

    // 7. pooling + props head
    hipLaunchKernelGGL(zero_kernel, dim3(4), dim3(256), 0, stream,
                       gsum, (long)N_GRAPHS * HID);
    hipLaunchKernelGGL(zero_kernel, dim3(1), dim3(64), 0, stream, gcnt, (long)N_GRAPHS);
    hipLaunchKernelGGL(pool_kernel, dim3((N_NODES + POOL_NODES - 1) / POOL_NODES), dim3(HID), 0,
                       stream, h, batch, gsum, gcnt);
    hipLaunchKernelGGL(props_kernel, dim3(N_GRAPHS), dim3(HID), 0, stream,
                       gsum, gcnt, pW1, pb1, pg, pbe, pW2, pb2, pred_props);
}